// Round 1
// baseline (739.677 us; speedup 1.0000x reference)
//
#include <hip/hip_runtime.h>
#include <math.h>

#define B_  16
#define C_  256
#define S_  1024
#define NH  4
#define DK  64
#define P3  768   // 3*NH*DK
#define ND  256   // NH*DK

// ---------------------------------------------------------------------------
// Kernel 1: QKV projection.
// qkv[b,s,n] = sum_c x[b,c,s] * w_proj[c,n] + b_proj[n],  n in [0,768)
// scatter into q/k/v each laid out [B][NH][S][DK].
// grid (S/64, P3/64, B), block 256. 64x64 tile, 4x4 per thread, BK=16.
// ---------------------------------------------------------------------------
__global__ __launch_bounds__(256) void qkv_proj(
    const float* __restrict__ x, const float* __restrict__ wp,
    const float* __restrict__ bp, float* __restrict__ q,
    float* __restrict__ k, float* __restrict__ v)
{
    __shared__ __align__(16) float As[16][64];   // [kk][ss]
    __shared__ __align__(16) float Bs[16][64];   // [kk][nn]
    const int tid = threadIdx.x;
    const int tx = tid & 15, ty = tid >> 4;
    const int s0 = blockIdx.x * 64, n0 = blockIdx.y * 64, b = blockIdx.z;

    float acc[4][4] = {};
    const int l64 = tid & 63, lk0 = tid >> 6;   // loader: 64 lanes per row

    for (int kc = 0; kc < C_; kc += 16) {
        __syncthreads();
        #pragma unroll
        for (int t = 0; t < 4; ++t) {
            int kk = lk0 + 4 * t;
            As[kk][l64] = x[((size_t)b * C_ + kc + kk) * S_ + s0 + l64];
            Bs[kk][l64] = wp[(size_t)(kc + kk) * P3 + n0 + l64];
        }
        __syncthreads();
        #pragma unroll
        for (int kk = 0; kk < 16; ++kk) {
            float4 a4 = *(const float4*)&As[kk][ty * 4];
            float4 b4 = *(const float4*)&Bs[kk][tx * 4];
            float av[4] = {a4.x, a4.y, a4.z, a4.w};
            float bv[4] = {b4.x, b4.y, b4.z, b4.w};
            #pragma unroll
            for (int i = 0; i < 4; ++i)
                #pragma unroll
                for (int j = 0; j < 4; ++j)
                    acc[i][j] += av[i] * bv[j];
        }
    }

    // epilogue: 4 consecutive n always fall inside one (h, q/k/v) 64-chunk
    const int n = n0 + tx * 4;
    const int h = n / 192, rem = n % 192;
    const int which = rem >> 6, d = rem & 63;
    float* dst = (which == 0) ? q : ((which == 1) ? k : v);
    float4 bias = *(const float4*)&bp[n];
    #pragma unroll
    for (int i = 0; i < 4; ++i) {
        int s = s0 + ty * 4 + i;
        float4 r;
        r.x = acc[i][0] + bias.x;
        r.y = acc[i][1] + bias.y;
        r.z = acc[i][2] + bias.z;
        r.w = acc[i][3] + bias.w;
        *(float4*)&dst[(((size_t)b * NH + h) * S_ + s) * DK + d] = r;
    }
}

// ---------------------------------------------------------------------------
// Kernel 2: flash-style attention, one block = (b, h, 32 query rows).
// Online softmax over 32-wide K/V tiles; o laid out [B][S][ND], n = h*64+d.
// Thread map: i = tid>>3 (row 0..31), qq = tid&7; row group = 8 lanes of one
// wave -> shfl_xor(1,2,4) row reductions. Thread owns d = qq*8..qq*8+7 of O.
// ---------------------------------------------------------------------------
__global__ __launch_bounds__(256) void attn(
    const float* __restrict__ q, const float* __restrict__ k,
    const float* __restrict__ v, float* __restrict__ o)
{
    __shared__ __align__(16) float Qs[32][68];
    __shared__ __align__(16) float Ks[32][68];
    __shared__ __align__(16) float Vs[32][68];
    __shared__ float Ps[32][33];

    const int tid = threadIdx.x;
    const int i  = tid >> 3;    // query row within tile
    const int qq = tid & 7;
    const int i0 = blockIdx.x * 32, h = blockIdx.y, b = blockIdx.z;

    const float* qb = q + (((size_t)b * NH + h) * S_ + i0) * DK;
    const float* kb = k + ((size_t)b * NH + h) * S_ * DK;
    const float* vb = v + ((size_t)b * NH + h) * S_ * DK;

    #pragma unroll
    for (int t = 0; t < 8; ++t) {
        int idx = t * 256 + tid;
        Qs[idx >> 6][idx & 63] = qb[idx];
    }

    float m = -INFINITY, l = 0.f;
    float oacc[8] = {};
    const float scale = 0.125f;   // DK^-0.5

    for (int jt = 0; jt < S_; jt += 32) {
        __syncthreads();
        #pragma unroll
        for (int t = 0; t < 8; ++t) {
            int idx = t * 256 + tid;
            Ks[idx >> 6][idx & 63] = kb[(size_t)jt * DK + idx];
            Vs[idx >> 6][idx & 63] = vb[(size_t)jt * DK + idx];
        }
        __syncthreads();

        // S[i][j] for j = qq + 8*jj
        float dot[4] = {0.f, 0.f, 0.f, 0.f};
        #pragma unroll
        for (int dd = 0; dd < 16; ++dd) {
            float4 qv = *(const float4*)&Qs[i][dd * 4];
            #pragma unroll
            for (int jj = 0; jj < 4; ++jj) {
                float4 kv = *(const float4*)&Ks[qq + 8 * jj][dd * 4];
                dot[jj] += qv.x * kv.x + qv.y * kv.y + qv.z * kv.z + qv.w * kv.w;
            }
        }
        #pragma unroll
        for (int jj = 0; jj < 4; ++jj) dot[jj] *= scale;

        // online softmax (row reduction across the 8-lane row group)
        float tmax = fmaxf(fmaxf(dot[0], dot[1]), fmaxf(dot[2], dot[3]));
        tmax = fmaxf(tmax, __shfl_xor(tmax, 1));
        tmax = fmaxf(tmax, __shfl_xor(tmax, 2));
        tmax = fmaxf(tmax, __shfl_xor(tmax, 4));
        float mnew  = fmaxf(m, tmax);
        float alpha = __expf(m - mnew);
        float ts = 0.f;
        #pragma unroll
        for (int jj = 0; jj < 4; ++jj) {
            float p = __expf(dot[jj] - mnew);
            ts += p;
            Ps[i][qq + 8 * jj] = p;
        }
        ts += __shfl_xor(ts, 1);
        ts += __shfl_xor(ts, 2);
        ts += __shfl_xor(ts, 4);
        l = l * alpha + ts;
        m = mnew;
        #pragma unroll
        for (int r = 0; r < 8; ++r) oacc[r] *= alpha;
        __syncthreads();   // P visible; Vs stable until next loop-top sync

        #pragma unroll
        for (int j = 0; j < 32; ++j) {
            float pj = Ps[i][j];
            float4 v0 = *(const float4*)&Vs[j][qq * 8];
            float4 v1 = *(const float4*)&Vs[j][qq * 8 + 4];
            oacc[0] += pj * v0.x;  oacc[1] += pj * v0.y;
            oacc[2] += pj * v0.z;  oacc[3] += pj * v0.w;
            oacc[4] += pj * v1.x;  oacc[5] += pj * v1.y;
            oacc[6] += pj * v1.z;  oacc[7] += pj * v1.w;
        }
    }

    const float inv = 1.f / l;
    const size_t base = ((size_t)b * S_ + i0 + i) * ND + h * DK + qq * 8;
    float4 r0, r1;
    r0.x = oacc[0] * inv; r0.y = oacc[1] * inv;
    r0.z = oacc[2] * inv; r0.w = oacc[3] * inv;
    r1.x = oacc[4] * inv; r1.y = oacc[5] * inv;
    r1.z = oacc[6] * inv; r1.w = oacc[7] * inv;
    *(float4*)&o[base]     = r0;
    *(float4*)&o[base + 4] = r1;
}

// ---------------------------------------------------------------------------
// Kernel 3: out[b,c,s] = sum_n o[b,s,n]*w_out[n,c] + b_out[c] + x[b,c,s]
// grid (S/64, C/64, B); output tile rows = c (ty), cols = s (tx) so stores
// along s are coalesced float4 and the residual x load shares the address.
// ---------------------------------------------------------------------------
__global__ __launch_bounds__(256) void out_proj(
    const float* __restrict__ o, const float* __restrict__ wo,
    const float* __restrict__ bo, const float* __restrict__ x,
    float* __restrict__ out)
{
    __shared__ __align__(16) float Ws[16][64];   // [kk][cc]
    __shared__ __align__(16) float Os[16][68];   // [kk][ss] (transposed store)
    const int tid = threadIdx.x;
    const int tx = tid & 15, ty = tid >> 4;
    const int s0 = blockIdx.x * 64, c0 = blockIdx.y * 64, b = blockIdx.z;

    float acc[4][4] = {};
    const int l64 = tid & 63, lk0 = tid >> 6;
    const int lkk = tid & 15, ls0 = tid >> 4;

    for (int kc = 0; kc < ND; kc += 16) {
        __syncthreads();
        #pragma unroll
        for (int t = 0; t < 4; ++t) {
            int kk = lk0 + 4 * t;
            Ws[kk][l64] = wo[(size_t)(kc + kk) * C_ + c0 + l64];
        }
        #pragma unroll
        for (int t = 0; t < 4; ++t) {
            int ss = ls0 + 16 * t;
            Os[lkk][ss] = o[((size_t)b * S_ + s0 + ss) * ND + kc + lkk];
        }
        __syncthreads();
        #pragma unroll
        for (int kk = 0; kk < 16; ++kk) {
            float4 a4 = *(const float4*)&Ws[kk][ty * 4];
            float4 b4 = *(const float4*)&Os[kk][tx * 4];
            float av[4] = {a4.x, a4.y, a4.z, a4.w};
            float bv[4] = {b4.x, b4.y, b4.z, b4.w};
            #pragma unroll
            for (int i = 0; i < 4; ++i)
                #pragma unroll
                for (int j = 0; j < 4; ++j)
                    acc[i][j] += av[i] * bv[j];
        }
    }

    #pragma unroll
    for (int i = 0; i < 4; ++i) {
        int c = c0 + ty * 4 + i;
        float bias = bo[c];
        size_t idx = ((size_t)b * C_ + c) * S_ + s0 + tx * 4;
        float4 xv = *(const float4*)&x[idx];
        float4 r;
        r.x = acc[i][0] + bias + xv.x;
        r.y = acc[i][1] + bias + xv.y;
        r.z = acc[i][2] + bias + xv.z;
        r.w = acc[i][3] + bias + xv.w;
        *(float4*)&out[idx] = r;
    }
}

// ---------------------------------------------------------------------------
extern "C" void kernel_launch(void* const* d_in, const int* in_sizes, int n_in,
                              void* d_out, int out_size, void* d_ws, size_t ws_size,
                              hipStream_t stream) {
    const float* x  = (const float*)d_in[0];
    const float* wp = (const float*)d_in[1];
    const float* bp = (const float*)d_in[2];
    const float* wo = (const float*)d_in[3];
    const float* bo = (const float*)d_in[4];
    float* out = (float*)d_out;

    // workspace: q,k,v [B][NH][S][DK] + o [B][S][ND], fp32 -> 64 MB total
    float* ws = (float*)d_ws;
    const size_t qkv_elems = (size_t)B_ * NH * S_ * DK;   // 4 Mi elems
    float* q = ws;
    float* k = q + qkv_elems;
    float* v = k + qkv_elems;
    float* o = v + qkv_elems;

    qkv_proj<<<dim3(S_ / 64, P3 / 64, B_), 256, 0, stream>>>(x, wp, bp, q, k, v);
    attn    <<<dim3(S_ / 32, NH, B_),      256, 0, stream>>>(q, k, v, o);
    out_proj<<<dim3(S_ / 64, C_ / 64, B_), 256, 0, stream>>>(o, wo, bo, x, out);
}

// Round 2
// 255.011 us; speedup vs baseline: 2.9006x; 2.9006x over previous
//
#include <hip/hip_runtime.h>
#include <math.h>

#define B_  16
#define C_  256
#define S_  1024
#define NH  4
#define DK  64
#define P3  768   // 3*NH*DK
#define ND  256   // NH*DK

typedef unsigned short u16;
typedef unsigned int   u32;
typedef float  f32x4  __attribute__((ext_vector_type(4)));
typedef short  bf16x8 __attribute__((ext_vector_type(8)));

__device__ __forceinline__ u16 f2bf(float f) {
    union { float f; u32 u; } x; x.f = f;
    u32 r = x.u + 0x7fffu + ((x.u >> 16) & 1u);   // RNE
    return (u16)(r >> 16);
}

// ---------------------------------------------------------------------------
// Kernel 1: QKV projection (fp32 GEMM, bf16 outputs).
// qkv[b,s,n] = sum_c x[b,c,s] * w_proj[c,n] + b_proj[n],  n in [0,768)
// q,k stored bf16 [B][NH][S][DK]; v stored bf16 TRANSPOSED [B][NH][DK][S].
// ---------------------------------------------------------------------------
__global__ __launch_bounds__(256) void qkv_proj(
    const float* __restrict__ x, const float* __restrict__ wp,
    const float* __restrict__ bp, u16* __restrict__ qo,
    u16* __restrict__ ko, u16* __restrict__ vo)
{
    __shared__ __align__(16) float As[16][64];   // [kk][ss]
    __shared__ __align__(16) float Bs[16][64];   // [kk][nn]
    const int tid = threadIdx.x;
    const int tx = tid & 15, ty = tid >> 4;
    const int s0 = blockIdx.x * 64, n0 = blockIdx.y * 64, b = blockIdx.z;

    float acc[4][4] = {};
    const int l64 = tid & 63, lk0 = tid >> 6;

    for (int kc = 0; kc < C_; kc += 16) {
        __syncthreads();
        #pragma unroll
        for (int t = 0; t < 4; ++t) {
            int kk = lk0 + 4 * t;
            As[kk][l64] = x[((size_t)b * C_ + kc + kk) * S_ + s0 + l64];
            Bs[kk][l64] = wp[(size_t)(kc + kk) * P3 + n0 + l64];
        }
        __syncthreads();
        #pragma unroll
        for (int kk = 0; kk < 16; ++kk) {
            float4 a4 = *(const float4*)&As[kk][ty * 4];
            float4 b4 = *(const float4*)&Bs[kk][tx * 4];
            float av[4] = {a4.x, a4.y, a4.z, a4.w};
            float bv[4] = {b4.x, b4.y, b4.z, b4.w};
            #pragma unroll
            for (int i = 0; i < 4; ++i)
                #pragma unroll
                for (int j = 0; j < 4; ++j)
                    acc[i][j] += av[i] * bv[j];
        }
    }

    // epilogue: n = h*192 + which*64 + d
    const int n = n0 + tx * 4;
    const int h = n / 192, rem = n % 192;
    const int which = rem >> 6, d = rem & 63;
    const int bh = b * NH + h;
    float4 bias = *(const float4*)&bp[n];
    float bj[4] = {bias.x, bias.y, bias.z, bias.w};

    if (which == 2) {
        // v transposed: [bh][dk][s], pack 4 consecutive s
        #pragma unroll
        for (int j = 0; j < 4; ++j) {
            u32 p0 = (u32)f2bf(acc[0][j] + bj[j]) | ((u32)f2bf(acc[1][j] + bj[j]) << 16);
            u32 p1 = (u32)f2bf(acc[2][j] + bj[j]) | ((u32)f2bf(acc[3][j] + bj[j]) << 16);
            uint2 u; u.x = p0; u.y = p1;
            *(uint2*)&vo[((size_t)bh * DK + d + j) * S_ + s0 + ty * 4] = u;
        }
    } else {
        u16* dst = (which == 0) ? qo : ko;
        #pragma unroll
        for (int i = 0; i < 4; ++i) {
            int s = s0 + ty * 4 + i;
            u32 p0 = (u32)f2bf(acc[i][0] + bj[0]) | ((u32)f2bf(acc[i][1] + bj[1]) << 16);
            u32 p1 = (u32)f2bf(acc[i][2] + bj[2]) | ((u32)f2bf(acc[i][3] + bj[3]) << 16);
            uint2 u; u.x = p0; u.y = p1;
            *(uint2*)&dst[((size_t)bh * S_ + s) * DK + d] = u;
        }
    }
}

// ---------------------------------------------------------------------------
// Kernel 2: flash attention with bf16 MFMA (16x16x32).
// Block = (b, h, 64 query rows) = 4 waves x 16 rows. Key tiles of 64.
// LDS rows padded to 72 bf16 so quarter-wave b128 frag reads are 2-way (free).
// A-layout: A[m=lane&15][k=quad*8+j]; C/D: col=lane&15, row=quad*4+reg.
// ---------------------------------------------------------------------------
__global__ __launch_bounds__(256) void attn_mfma(
    const u16* __restrict__ q, const u16* __restrict__ k,
    const u16* __restrict__ vt, float* __restrict__ o)
{
    __shared__ __align__(16) u16 Ks[64][72];      // [key][dk]
    __shared__ __align__(16) u16 Vs[64][72];      // [dk][key]  (transposed V)
    __shared__ __align__(16) u16 Ps[4][16][72];   // per-wave [q][key]

    const int tid = threadIdx.x;
    const int wave = tid >> 6, lane = tid & 63;
    const int n = lane & 15, quad = lane >> 4;
    const int i0 = blockIdx.x * 64, h = blockIdx.y, b = blockIdx.z;
    const int bh = b * NH + h;

    const u16* kb = k  + (size_t)bh * S_ * DK;
    const u16* vb = vt + (size_t)bh * DK * S_;

    // Q fragments (A-layout), query rows i0 + wave*16 + (lane&15)
    const u16* qrow = q + ((size_t)bh * S_ + i0 + wave * 16 + n) * DK;
    bf16x8 qf0 = *(const bf16x8*)&qrow[quad * 8];
    bf16x8 qf1 = *(const bf16x8*)&qrow[32 + quad * 8];

    float mrow[4], lrow[4];
    #pragma unroll
    for (int r = 0; r < 4; ++r) { mrow[r] = -INFINITY; lrow[r] = 0.f; }
    f32x4 oacc[4];
    #pragma unroll
    for (int nb = 0; nb < 4; ++nb)
        #pragma unroll
        for (int r = 0; r < 4; ++r) oacc[nb][r] = 0.f;

    for (int jt = 0; jt < S_; jt += 64) {
        __syncthreads();
        // stage K[64 keys][64 dk] and Vt[64 dk][64 keys]; 16B chunks
        #pragma unroll
        for (int t2 = 0; t2 < 2; ++t2) {
            int c = tid + t2 * 256;
            int row = c >> 3, col = (c & 7) * 8;
            *(bf16x8*)&Ks[row][col] = *(const bf16x8*)&kb[(size_t)(jt + row) * DK + col];
            *(bf16x8*)&Vs[row][col] = *(const bf16x8*)&vb[(size_t)row * S_ + jt + col];
        }
        __syncthreads();

        // S = Q K^T : per wave [16 q][64 keys] in 4 C-frags
        f32x4 sb[4];
        #pragma unroll
        for (int nb = 0; nb < 4; ++nb) {
            f32x4 acc; acc[0] = 0.f; acc[1] = 0.f; acc[2] = 0.f; acc[3] = 0.f;
            bf16x8 kf0 = *(const bf16x8*)&Ks[nb * 16 + n][quad * 8];
            bf16x8 kf1 = *(const bf16x8*)&Ks[nb * 16 + n][32 + quad * 8];
            acc = __builtin_amdgcn_mfma_f32_16x16x32_bf16(qf0, kf0, acc, 0, 0, 0);
            acc = __builtin_amdgcn_mfma_f32_16x16x32_bf16(qf1, kf1, acc, 0, 0, 0);
            sb[nb] = acc;
        }
        #pragma unroll
        for (int nb = 0; nb < 4; ++nb)
            #pragma unroll
            for (int r = 0; r < 4; ++r) sb[nb][r] *= 0.125f;

        // online softmax; row = quad*4 + r
        float mx[4];
        #pragma unroll
        for (int r = 0; r < 4; ++r) {
            mx[r] = fmaxf(fmaxf(sb[0][r], sb[1][r]), fmaxf(sb[2][r], sb[3][r]));
            mx[r] = fmaxf(mx[r], __shfl_xor(mx[r], 1));
            mx[r] = fmaxf(mx[r], __shfl_xor(mx[r], 2));
            mx[r] = fmaxf(mx[r], __shfl_xor(mx[r], 4));
            mx[r] = fmaxf(mx[r], __shfl_xor(mx[r], 8));
        }
        float al[4];
        #pragma unroll
        for (int r = 0; r < 4; ++r) {
            float mn = fmaxf(mrow[r], mx[r]);
            al[r] = __expf(mrow[r] - mn);
            mrow[r] = mn;
        }
        float sum[4] = {0.f, 0.f, 0.f, 0.f};
        #pragma unroll
        for (int nb = 0; nb < 4; ++nb)
            #pragma unroll
            for (int r = 0; r < 4; ++r) {
                float p = __expf(sb[nb][r] - mrow[r]);
                sum[r] += p;
                Ps[wave][quad * 4 + r][nb * 16 + n] = f2bf(p);
            }
        #pragma unroll
        for (int r = 0; r < 4; ++r) {
            sum[r] += __shfl_xor(sum[r], 1);
            sum[r] += __shfl_xor(sum[r], 2);
            sum[r] += __shfl_xor(sum[r], 4);
            sum[r] += __shfl_xor(sum[r], 8);
            lrow[r] = lrow[r] * al[r] + sum[r];
        }
        #pragma unroll
        for (int nb = 0; nb < 4; ++nb)
            #pragma unroll
            for (int r = 0; r < 4; ++r) oacc[nb][r] *= al[r];

        // O += P V : A = P (round-tripped to A-layout), B = Vt frags
        bf16x8 pa0 = *(const bf16x8*)&Ps[wave][n][quad * 8];
        bf16x8 pa1 = *(const bf16x8*)&Ps[wave][n][32 + quad * 8];
        #pragma unroll
        for (int nbd = 0; nbd < 4; ++nbd) {
            bf16x8 vf0 = *(const bf16x8*)&Vs[nbd * 16 + n][quad * 8];
            bf16x8 vf1 = *(const bf16x8*)&Vs[nbd * 16 + n][32 + quad * 8];
            oacc[nbd] = __builtin_amdgcn_mfma_f32_16x16x32_bf16(pa0, vf0, oacc[nbd], 0, 0, 0);
            oacc[nbd] = __builtin_amdgcn_mfma_f32_16x16x32_bf16(pa1, vf1, oacc[nbd], 0, 0, 0);
        }
    }

    // epilogue: o[b][s][h*64+dk], s = i0 + wave*16 + quad*4 + r, dk = nbd*16+n
    float* ob = o + ((size_t)b * S_ + i0 + wave * 16 + quad * 4) * ND + h * DK + n;
    #pragma unroll
    for (int r = 0; r < 4; ++r) {
        float inv = 1.f / lrow[r];
        #pragma unroll
        for (int nbd = 0; nbd < 4; ++nbd)
            ob[(size_t)r * ND + nbd * 16] = oacc[nbd][r] * inv;
    }
}

// ---------------------------------------------------------------------------
// Kernel 3: out[b,c,s] = sum_n o[b,s,n]*w_out[n,c] + b_out[c] + x[b,c,s]
// ---------------------------------------------------------------------------
__global__ __launch_bounds__(256) void out_proj(
    const float* __restrict__ o, const float* __restrict__ wo,
    const float* __restrict__ bo, const float* __restrict__ x,
    float* __restrict__ out)
{
    __shared__ __align__(16) float Ws[16][64];   // [kk][cc]
    __shared__ __align__(16) float Os[16][68];   // [kk][ss]
    const int tid = threadIdx.x;
    const int tx = tid & 15, ty = tid >> 4;
    const int s0 = blockIdx.x * 64, c0 = blockIdx.y * 64, b = blockIdx.z;

    float acc[4][4] = {};
    const int l64 = tid & 63, lk0 = tid >> 6;
    const int lkk = tid & 15, ls0 = tid >> 4;

    for (int kc = 0; kc < ND; kc += 16) {
        __syncthreads();
        #pragma unroll
        for (int t = 0; t < 4; ++t) {
            int kk = lk0 + 4 * t;
            Ws[kk][l64] = wo[(size_t)(kc + kk) * C_ + c0 + l64];
        }
        #pragma unroll
        for (int t = 0; t < 4; ++t) {
            int ss = ls0 + 16 * t;
            Os[lkk][ss] = o[((size_t)b * S_ + s0 + ss) * ND + kc + lkk];
        }
        __syncthreads();
        #pragma unroll
        for (int kk = 0; kk < 16; ++kk) {
            float4 a4 = *(const float4*)&Ws[kk][ty * 4];
            float4 b4 = *(const float4*)&Os[kk][tx * 4];
            float av[4] = {a4.x, a4.y, a4.z, a4.w};
            float bv[4] = {b4.x, b4.y, b4.z, b4.w};
            #pragma unroll
            for (int i = 0; i < 4; ++i)
                #pragma unroll
                for (int j = 0; j < 4; ++j)
                    acc[i][j] += av[i] * bv[j];
        }
    }

    #pragma unroll
    for (int i = 0; i < 4; ++i) {
        int c = c0 + ty * 4 + i;
        float bias = bo[c];
        size_t idx = ((size_t)b * C_ + c) * S_ + s0 + tx * 4;
        float4 xv = *(const float4*)&x[idx];
        float4 r;
        r.x = acc[i][0] + bias + xv.x;
        r.y = acc[i][1] + bias + xv.y;
        r.z = acc[i][2] + bias + xv.z;
        r.w = acc[i][3] + bias + xv.w;
        *(float4*)&out[idx] = r;
    }
}

// ---------------------------------------------------------------------------
extern "C" void kernel_launch(void* const* d_in, const int* in_sizes, int n_in,
                              void* d_out, int out_size, void* d_ws, size_t ws_size,
                              hipStream_t stream) {
    const float* x  = (const float*)d_in[0];
    const float* wp = (const float*)d_in[1];
    const float* bp = (const float*)d_in[2];
    const float* wo = (const float*)d_in[3];
    const float* bo = (const float*)d_in[4];
    float* out = (float*)d_out;

    // workspace: q,k bf16 [B][NH][S][DK]; v bf16 [B][NH][DK][S]; o fp32 [B][S][ND]
    const size_t qkv_elems = (size_t)B_ * NH * S_ * DK;   // 4 Mi
    u16* q = (u16*)d_ws;
    u16* k = q + qkv_elems;
    u16* v = k + qkv_elems;
    float* o = (float*)(v + qkv_elems);

    qkv_proj <<<dim3(S_ / 64, P3 / 64, B_), 256, 0, stream>>>(x, wp, bp, q, k, v);
    attn_mfma<<<dim3(S_ / 64, NH, B_),      256, 0, stream>>>(q, k, v, o);
    out_proj <<<dim3(S_ / 64, C_ / 64, B_), 256, 0, stream>>>(o, wo, bo, x, out);
}

// Round 3
// 178.560 us; speedup vs baseline: 4.1425x; 1.4282x over previous
//
#include <hip/hip_runtime.h>
#include <math.h>

#define B_  16
#define C_  256
#define S_  1024
#define NH  4
#define DK  64
#define P3  768   // 3*NH*DK
#define ND  256   // NH*DK

typedef unsigned short u16;
typedef unsigned int   u32;
typedef float  f32x4  __attribute__((ext_vector_type(4)));
typedef short  bf16x8 __attribute__((ext_vector_type(8)));

__device__ __forceinline__ u16 f2bf(float f) {
    union { float f; u32 u; } x; x.f = f;
    u32 r = x.u + 0x7fffu + ((x.u >> 16) & 1u);   // RNE
    return (u16)(r >> 16);
}

// async global->LDS, 16B per lane; LDS dest is wave-uniform base + lane*16
__device__ __forceinline__ void stage16(const u16* g, u16* l) {
    __builtin_amdgcn_global_load_lds(
        (const __attribute__((address_space(1))) void*)g,
        (__attribute__((address_space(3))) void*)l, 16, 0, 0);
}

// ---------------------------------------------------------------------------
// Generic tiled transpose + fp32->bf16 convert: src[z][R][Cc] -> dst[z][Cc][R]
// grid (Cc/64, R/64, z), block 256.
// ---------------------------------------------------------------------------
__global__ __launch_bounds__(256) void transpose_cvt(
    const float* __restrict__ src, u16* __restrict__ dst, int R, int Cc)
{
    __shared__ float T[64][65];
    const int tid = threadIdx.x;
    const int c0 = blockIdx.x * 64, r0 = blockIdx.y * 64, z = blockIdx.z;
    src += (size_t)z * R * Cc;
    dst += (size_t)z * R * Cc;

    const int l64 = tid & 63, rr0 = tid >> 6;
    #pragma unroll
    for (int t = 0; t < 16; ++t) {
        int rr = rr0 + t * 4;
        T[rr][l64] = src[(size_t)(r0 + rr) * Cc + c0 + l64];
    }
    __syncthreads();
    const int rp = tid & 31;     // r-pair
    const int cb = tid >> 5;     // 0..7
    #pragma unroll
    for (int t = 0; t < 8; ++t) {
        int c = cb + t * 8;
        u32 lo = f2bf(T[2 * rp][c]);
        u32 hi = f2bf(T[2 * rp + 1][c]);
        *(u32*)&dst[(size_t)(c0 + c) * R + r0 + 2 * rp] = lo | (hi << 16);
    }
}

// ---------------------------------------------------------------------------
// Kernel: QKV projection, bf16 MFMA.
// A = xt[b][s][c], B = wpT[n][c]; C[s][n] + bias -> q/k [bh][s][dk], vt [bh][dk][s]
// Frag-major LDS: chunk = [blk16][half], slot = chunk*512 + lane*8 u16.
// ---------------------------------------------------------------------------
__global__ __launch_bounds__(256) void qkv_mfma(
    const u16* __restrict__ xt, const u16* __restrict__ wpT,
    const float* __restrict__ bp, u16* __restrict__ qo,
    u16* __restrict__ ko, u16* __restrict__ vo)
{
    __shared__ __align__(16) u16 As[4096];
    __shared__ __align__(16) u16 Bs[4096];
    __shared__ __align__(16) u16 Cs[64][72];

    const int tid = threadIdx.x;
    const int wave = tid >> 6, lane = tid & 63;
    const int n_ = lane & 15, quad = lane >> 4;
    const int s0 = blockIdx.x * 64, n0 = blockIdx.y * 64, b = blockIdx.z;

    const u16* arow = xt  + ((size_t)b * S_ + s0 + wave * 16 + n_) * C_ + quad * 8;
    const u16* brow = wpT + (size_t)(n0 + wave * 16 + n_) * C_ + quad * 8;
    u16* aslot = &As[wave * 1024];
    u16* bslot = &Bs[wave * 1024];

    f32x4 acc[4];
    #pragma unroll
    for (int nb = 0; nb < 4; ++nb)
        #pragma unroll
        for (int r = 0; r < 4; ++r) acc[nb][r] = 0.f;

    for (int kc = 0; kc < C_; kc += 64) {
        __syncthreads();
        stage16(arow + kc,      aslot);
        stage16(arow + kc + 32, aslot + 512);
        stage16(brow + kc,      bslot);
        stage16(brow + kc + 32, bslot + 512);
        __syncthreads();
        bf16x8 af0 = *(const bf16x8*)&As[wave * 1024 + lane * 8];
        bf16x8 af1 = *(const bf16x8*)&As[wave * 1024 + 512 + lane * 8];
        #pragma unroll
        for (int nb = 0; nb < 4; ++nb) {
            bf16x8 bf0 = *(const bf16x8*)&Bs[nb * 1024 + lane * 8];
            bf16x8 bf1 = *(const bf16x8*)&Bs[nb * 1024 + 512 + lane * 8];
            acc[nb] = __builtin_amdgcn_mfma_f32_16x16x32_bf16(af0, bf0, acc[nb], 0, 0, 0);
            acc[nb] = __builtin_amdgcn_mfma_f32_16x16x32_bf16(af1, bf1, acc[nb], 0, 0, 0);
        }
    }

    // epilogue: n0 block maps to single (head, which) 64-chunk
    const int hd = n0 / 192, rem = n0 % 192, which = rem / 64;
    const int bh = b * NH + hd;
    float bias[4];
    #pragma unroll
    for (int nb = 0; nb < 4; ++nb) bias[nb] = bp[n0 + nb * 16 + n_];

    const int srow = wave * 16 + quad * 4;
    __syncthreads();
    if (which < 2) {
        #pragma unroll
        for (int nb = 0; nb < 4; ++nb)
            #pragma unroll
            for (int r = 0; r < 4; ++r)
                Cs[srow + r][nb * 16 + n_] = f2bf(acc[nb][r] + bias[nb]);
    } else {
        #pragma unroll
        for (int nb = 0; nb < 4; ++nb)
            #pragma unroll
            for (int r = 0; r < 4; ++r)
                Cs[nb * 16 + n_][srow + r] = f2bf(acc[nb][r] + bias[nb]);
    }
    __syncthreads();

    u16* dst = (which == 0) ? qo : ((which == 1) ? ko : vo);
    #pragma unroll
    for (int t = 0; t < 2; ++t) {
        int ii = tid + t * 256;
        int row = ii >> 3, c8 = (ii & 7) * 8;
        bf16x8 val = *(const bf16x8*)&Cs[row][c8];
        size_t addr = (which < 2)
            ? ((size_t)bh * S_ + s0 + row) * DK + c8          // [bh][s][dk]
            : ((size_t)bh * DK + row) * S_ + s0 + c8;         // [bh][dk][s]
        *(bf16x8*)&dst[addr] = val;
    }
}

// ---------------------------------------------------------------------------
// Kernel: flash attention, bf16 MFMA, frag-major staging.
// Block = (b, head, 64 q rows) = 4 waves x 16 rows; 64-key tiles.
// ---------------------------------------------------------------------------
__global__ __launch_bounds__(256) void attn_mfma(
    const u16* __restrict__ q, const u16* __restrict__ k,
    const u16* __restrict__ vt, u16* __restrict__ obf)
{
    __shared__ __align__(16) u16 Ks[4096];
    __shared__ __align__(16) u16 Vs[4096];
    __shared__ __align__(16) u16 Ps[4][1024];   // per-wave P (16q x 64key)

    const int tid = threadIdx.x;
    const int wave = tid >> 6, lane = tid & 63;
    const int n_ = lane & 15, quad = lane >> 4;
    const int i0 = blockIdx.x * 64;
    const int hd = blockIdx.y, b = blockIdx.z;
    const int bh = b * NH + hd;

    const u16* qrow = q + ((size_t)bh * S_ + i0 + wave * 16 + n_) * DK;
    bf16x8 qf0 = *(const bf16x8*)&qrow[quad * 8];
    bf16x8 qf1 = *(const bf16x8*)&qrow[32 + quad * 8];

    const u16* kbase = k  + ((size_t)bh * S_ + wave * 16 + n_) * DK + quad * 8;
    const u16* vbase = vt + ((size_t)bh * DK + wave * 16 + n_) * S_ + quad * 8;
    u16* kslot = &Ks[wave * 1024];
    u16* vslot = &Vs[wave * 1024];
    u16* pw = Ps[wave];

    // P scatter-write bases: element (m=quad*4+r, key=nb*16+n_) ->
    // slot (h=nb>>1, qp=(nb*2+(n_>>3))&3, L=qp*16+m), j=n_&7
    int pbase[4];
    #pragma unroll
    for (int nb = 0; nb < 4; ++nb) {
        int hp = nb >> 1;
        int qp = (nb * 2 + (n_ >> 3)) & 3;
        pbase[nb] = (hp * 64 + qp * 16) * 8 + (n_ & 7) + quad * 32;
    }

    float mrow[4], lrow[4];
    #pragma unroll
    for (int r = 0; r < 4; ++r) { mrow[r] = -INFINITY; lrow[r] = 0.f; }
    f32x4 oacc[4];
    #pragma unroll
    for (int nb = 0; nb < 4; ++nb)
        #pragma unroll
        for (int r = 0; r < 4; ++r) oacc[nb][r] = 0.f;

    for (int jt = 0; jt < S_; jt += 64) {
        __syncthreads();
        stage16(kbase + (size_t)jt * DK,      kslot);
        stage16(kbase + (size_t)jt * DK + 32, kslot + 512);
        stage16(vbase + jt,                   vslot);
        stage16(vbase + jt + 32,              vslot + 512);
        __syncthreads();

        f32x4 sb[4];
        #pragma unroll
        for (int nb = 0; nb < 4; ++nb) {
            f32x4 a; a[0] = a[1] = a[2] = a[3] = 0.f;
            bf16x8 kf0 = *(const bf16x8*)&Ks[nb * 1024 + lane * 8];
            bf16x8 kf1 = *(const bf16x8*)&Ks[nb * 1024 + 512 + lane * 8];
            a = __builtin_amdgcn_mfma_f32_16x16x32_bf16(qf0, kf0, a, 0, 0, 0);
            a = __builtin_amdgcn_mfma_f32_16x16x32_bf16(qf1, kf1, a, 0, 0, 0);
            sb[nb] = a;
        }
        #pragma unroll
        for (int nb = 0; nb < 4; ++nb)
            #pragma unroll
            for (int r = 0; r < 4; ++r) sb[nb][r] *= 0.125f;

        float mx[4];
        #pragma unroll
        for (int r = 0; r < 4; ++r) {
            mx[r] = fmaxf(fmaxf(sb[0][r], sb[1][r]), fmaxf(sb[2][r], sb[3][r]));
            mx[r] = fmaxf(mx[r], __shfl_xor(mx[r], 1));
            mx[r] = fmaxf(mx[r], __shfl_xor(mx[r], 2));
            mx[r] = fmaxf(mx[r], __shfl_xor(mx[r], 4));
            mx[r] = fmaxf(mx[r], __shfl_xor(mx[r], 8));
        }
        float al[4];
        #pragma unroll
        for (int r = 0; r < 4; ++r) {
            float mn = fmaxf(mrow[r], mx[r]);
            al[r] = __expf(mrow[r] - mn);
            mrow[r] = mn;
        }
        float sum[4] = {0.f, 0.f, 0.f, 0.f};
        #pragma unroll
        for (int nb = 0; nb < 4; ++nb)
            #pragma unroll
            for (int r = 0; r < 4; ++r) {
                float p = __expf(sb[nb][r] - mrow[r]);
                sum[r] += p;
                pw[pbase[nb] + r * 8] = f2bf(p);
            }
        #pragma unroll
        for (int r = 0; r < 4; ++r) {
            sum[r] += __shfl_xor(sum[r], 1);
            sum[r] += __shfl_xor(sum[r], 2);
            sum[r] += __shfl_xor(sum[r], 4);
            sum[r] += __shfl_xor(sum[r], 8);
            lrow[r] = lrow[r] * al[r] + sum[r];
        }
        #pragma unroll
        for (int nb = 0; nb < 4; ++nb)
            #pragma unroll
            for (int r = 0; r < 4; ++r) oacc[nb][r] *= al[r];

        bf16x8 pa0 = *(const bf16x8*)&pw[lane * 8];
        bf16x8 pa1 = *(const bf16x8*)&pw[512 + lane * 8];
        #pragma unroll
        for (int nbd = 0; nbd < 4; ++nbd) {
            bf16x8 vf0 = *(const bf16x8*)&Vs[nbd * 1024 + lane * 8];
            bf16x8 vf1 = *(const bf16x8*)&Vs[nbd * 1024 + 512 + lane * 8];
            oacc[nbd] = __builtin_amdgcn_mfma_f32_16x16x32_bf16(pa0, vf0, oacc[nbd], 0, 0, 0);
            oacc[nbd] = __builtin_amdgcn_mfma_f32_16x16x32_bf16(pa1, vf1, oacc[nbd], 0, 0, 0);
        }
    }

    // epilogue: reuse pw as row-major [16 q][64 dk] bf16, then b128 stores
    float inv[4];
    #pragma unroll
    for (int r = 0; r < 4; ++r) inv[r] = 1.f / lrow[r];
    #pragma unroll
    for (int nbd = 0; nbd < 4; ++nbd)
        #pragma unroll
        for (int r = 0; r < 4; ++r)
            pw[(quad * 4 + r) * 64 + nbd * 16 + n_] = f2bf(oacc[nbd][r] * inv[r]);
    #pragma unroll
    for (int t = 0; t < 2; ++t) {
        int ii = lane + t * 64;
        int row = ii >> 3, c8 = (ii & 7) * 8;
        bf16x8 vv = *(const bf16x8*)&pw[row * 64 + c8];
        *(bf16x8*)&obf[((size_t)b * S_ + i0 + wave * 16 + row) * ND + hd * DK + c8] = vv;
    }
}

// ---------------------------------------------------------------------------
// Kernel: out projection, bf16 MFMA + fp32 epilogue (bias + residual).
// A = obf[b][s][n], B = woT[c][n]; out[b][c][s] = C[s][c]^T + bo[c] + x[b][c][s]
// ---------------------------------------------------------------------------
__global__ __launch_bounds__(256) void out_proj_mfma(
    const u16* __restrict__ obf, const u16* __restrict__ woT,
    const float* __restrict__ bo, const float* __restrict__ x,
    float* __restrict__ out)
{
    __shared__ __align__(16) u16 As[4096];
    __shared__ __align__(16) u16 Bs[4096];
    __shared__ __align__(16) float Ct[64][68];

    const int tid = threadIdx.x;
    const int wave = tid >> 6, lane = tid & 63;
    const int n_ = lane & 15, quad = lane >> 4;
    const int s0 = blockIdx.x * 64, c0 = blockIdx.y * 64, b = blockIdx.z;

    const u16* arow = obf + ((size_t)b * S_ + s0 + wave * 16 + n_) * ND + quad * 8;
    const u16* brow = woT + (size_t)(c0 + wave * 16 + n_) * ND + quad * 8;
    u16* aslot = &As[wave * 1024];
    u16* bslot = &Bs[wave * 1024];

    f32x4 acc[4];
    #pragma unroll
    for (int nb = 0; nb < 4; ++nb)
        #pragma unroll
        for (int r = 0; r < 4; ++r) acc[nb][r] = 0.f;

    for (int kc = 0; kc < ND; kc += 64) {
        __syncthreads();
        stage16(arow + kc,      aslot);
        stage16(arow + kc + 32, aslot + 512);
        stage16(brow + kc,      bslot);
        stage16(brow + kc + 32, bslot + 512);
        __syncthreads();
        bf16x8 af0 = *(const bf16x8*)&As[wave * 1024 + lane * 8];
        bf16x8 af1 = *(const bf16x8*)&As[wave * 1024 + 512 + lane * 8];
        #pragma unroll
        for (int nb = 0; nb < 4; ++nb) {
            bf16x8 bf0 = *(const bf16x8*)&Bs[nb * 1024 + lane * 8];
            bf16x8 bf1 = *(const bf16x8*)&Bs[nb * 1024 + 512 + lane * 8];
            acc[nb] = __builtin_amdgcn_mfma_f32_16x16x32_bf16(af0, bf0, acc[nb], 0, 0, 0);
            acc[nb] = __builtin_amdgcn_mfma_f32_16x16x32_bf16(af1, bf1, acc[nb], 0, 0, 0);
        }
    }

    const int srow = wave * 16 + quad * 4;
    __syncthreads();
    #pragma unroll
    for (int nb = 0; nb < 4; ++nb)
        #pragma unroll
        for (int r = 0; r < 4; ++r)
            Ct[nb * 16 + n_][srow + r] = acc[nb][r];
    __syncthreads();

    #pragma unroll
    for (int t = 0; t < 4; ++t) {
        int ii = tid + t * 256;
        int row = ii >> 4, ch = (ii & 15) * 4;
        float4 cv = *(const float4*)&Ct[row][ch];
        float bias = bo[c0 + row];
        size_t idx = ((size_t)b * C_ + c0 + row) * S_ + s0 + ch;
        float4 xv = *(const float4*)&x[idx];
        float4 rr;
        rr.x = cv.x + bias + xv.x;
        rr.y = cv.y + bias + xv.y;
        rr.z = cv.z + bias + xv.z;
        rr.w = cv.w + bias + xv.w;
        *(float4*)&out[idx] = rr;
    }
}

// ---------------------------------------------------------------------------
extern "C" void kernel_launch(void* const* d_in, const int* in_sizes, int n_in,
                              void* d_out, int out_size, void* d_ws, size_t ws_size,
                              hipStream_t stream) {
    const float* x  = (const float*)d_in[0];
    const float* wp = (const float*)d_in[1];
    const float* bp = (const float*)d_in[2];
    const float* wo = (const float*)d_in[3];
    const float* bo = (const float*)d_in[4];
    float* out = (float*)d_out;

    const size_t QKV_E = (size_t)B_ * NH * S_ * DK;   // 4 Mi
    u16* q   = (u16*)d_ws;
    u16* kk  = q   + QKV_E;
    u16* vtp = kk  + QKV_E;
    u16* obf = vtp + QKV_E;                            // B*S*ND
    u16* xt  = obf + (size_t)B_ * S_ * ND;             // B*S*C
    u16* wpT = xt  + (size_t)B_ * S_ * C_;             // P3*C
    u16* woT = wpT + (size_t)P3 * C_;                  // C*ND

    transpose_cvt<<<dim3(S_ / 64, C_ / 64, B_), 256, 0, stream>>>(x, xt, C_, S_);
    transpose_cvt<<<dim3(P3 / 64, C_ / 64, 1), 256, 0, stream>>>(wp, wpT, C_, P3);
    transpose_cvt<<<dim3(C_ / 64, ND / 64, 1), 256, 0, stream>>>(wo, woT, ND, C_);
    qkv_mfma     <<<dim3(S_ / 64, P3 / 64, B_), 256, 0, stream>>>(xt, wpT, bp, q, kk, vtp);
    attn_mfma    <<<dim3(S_ / 64, NH, B_),      256, 0, stream>>>(q, kk, vtp, obf);
    out_proj_mfma<<<dim3(S_ / 64, C_ / 64, B_), 256, 0, stream>>>(obf, woT, bo, x, out);
}

// Round 4
// 156.290 us; speedup vs baseline: 4.7327x; 1.1425x over previous
//
#include <hip/hip_runtime.h>
#include <math.h>

#define B_  16
#define C_  256
#define S_  1024
#define NH  4
#define DK  64
#define P3  768   // 3*NH*DK
#define ND  256   // NH*DK

typedef unsigned short u16;
typedef unsigned int   u32;
typedef float  f32x4  __attribute__((ext_vector_type(4)));
typedef short  bf16x8 __attribute__((ext_vector_type(8)));

__device__ __forceinline__ u16 f2bf(float f) {
    union { float f; u32 u; } x; x.f = f;
    u32 r = x.u + 0x7fffu + ((x.u >> 16) & 1u);   // RNE
    return (u16)(r >> 16);
}

// async global->LDS, 16B per lane; LDS dest is wave-uniform base + lane*16
__device__ __forceinline__ void stage16(const u16* g, u16* l) {
    __builtin_amdgcn_global_load_lds(
        (const __attribute__((address_space(1))) void*)g,
        (__attribute__((address_space(3))) void*)l, 16, 0, 0);
}

// ---------------------------------------------------------------------------
// Generic tiled transpose + fp32->bf16 convert: src[z][R][Cc] -> dst[z][Cc][R]
// ---------------------------------------------------------------------------
__global__ __launch_bounds__(256) void transpose_cvt(
    const float* __restrict__ src, u16* __restrict__ dst, int R, int Cc)
{
    __shared__ float T[64][65];
    const int tid = threadIdx.x;
    const int c0 = blockIdx.x * 64, r0 = blockIdx.y * 64, z = blockIdx.z;
    src += (size_t)z * R * Cc;
    dst += (size_t)z * R * Cc;

    const int l64 = tid & 63, rr0 = tid >> 6;
    #pragma unroll
    for (int t = 0; t < 16; ++t) {
        int rr = rr0 + t * 4;
        T[rr][l64] = src[(size_t)(r0 + rr) * Cc + c0 + l64];
    }
    __syncthreads();
    const int rp = tid & 31;
    const int cb = tid >> 5;
    #pragma unroll
    for (int t = 0; t < 8; ++t) {
        int c = cb + t * 8;
        u32 lo = f2bf(T[2 * rp][c]);
        u32 hi = f2bf(T[2 * rp + 1][c]);
        *(u32*)&dst[(size_t)(c0 + c) * R + r0 + 2 * rp] = lo | (hi << 16);
    }
}

// ---------------------------------------------------------------------------
// Kernel: QKV projection, bf16 MFMA, BK=128 (2 K-iters, 16 MFMA per barrier).
// A = xt[b][s][c], B = wpT[n][c]; C[s][n] + bias -> q/k [bh][s][dk], vt [bh][dk][s]
// Frag-major LDS: wave/nb group g, chunk c2 -> (g*4+c2)*512 + lane*8 u16.
// ---------------------------------------------------------------------------
__global__ __launch_bounds__(256) void qkv_mfma(
    const u16* __restrict__ xt, const u16* __restrict__ wpT,
    const float* __restrict__ bp, u16* __restrict__ qo,
    u16* __restrict__ ko, u16* __restrict__ vo)
{
    __shared__ __align__(16) u16 As[8192];
    __shared__ __align__(16) u16 Bs[8192];
    __shared__ __align__(16) u16 Cs[64][72];

    const int tid = threadIdx.x;
    const int wave = tid >> 6, lane = tid & 63;
    const int n_ = lane & 15, quad = lane >> 4;
    const int s0 = blockIdx.x * 64, n0 = blockIdx.y * 64, b = blockIdx.z;

    const u16* arow = xt  + ((size_t)b * S_ + s0 + wave * 16 + n_) * C_ + quad * 8;
    const u16* brow = wpT + (size_t)(n0 + wave * 16 + n_) * C_ + quad * 8;
    u16* aslot = &As[wave * 2048];
    u16* bslot = &Bs[wave * 2048];

    f32x4 acc[4];
    #pragma unroll
    for (int nb = 0; nb < 4; ++nb)
        #pragma unroll
        for (int r = 0; r < 4; ++r) acc[nb][r] = 0.f;

    #pragma unroll
    for (int kc = 0; kc < C_; kc += 128) {
        __syncthreads();
        #pragma unroll
        for (int c2 = 0; c2 < 4; ++c2) {
            stage16(arow + kc + c2 * 32, aslot + c2 * 512);
            stage16(brow + kc + c2 * 32, bslot + c2 * 512);
        }
        __syncthreads();
        #pragma unroll
        for (int c2 = 0; c2 < 4; ++c2) {
            bf16x8 af = *(const bf16x8*)&As[wave * 2048 + c2 * 512 + lane * 8];
            #pragma unroll
            for (int nb = 0; nb < 4; ++nb) {
                bf16x8 bf = *(const bf16x8*)&Bs[nb * 2048 + c2 * 512 + lane * 8];
                acc[nb] = __builtin_amdgcn_mfma_f32_16x16x32_bf16(af, bf, acc[nb], 0, 0, 0);
            }
        }
    }

    const int hd = n0 / 192, rem = n0 % 192, which = rem / 64;
    const int bh = b * NH + hd;
    float bias[4];
    #pragma unroll
    for (int nb = 0; nb < 4; ++nb) bias[nb] = bp[n0 + nb * 16 + n_];

    const int srow = wave * 16 + quad * 4;
    __syncthreads();
    if (which < 2) {
        #pragma unroll
        for (int nb = 0; nb < 4; ++nb)
            #pragma unroll
            for (int r = 0; r < 4; ++r)
                Cs[srow + r][nb * 16 + n_] = f2bf(acc[nb][r] + bias[nb]);
    } else {
        #pragma unroll
        for (int nb = 0; nb < 4; ++nb)
            #pragma unroll
            for (int r = 0; r < 4; ++r)
                Cs[nb * 16 + n_][srow + r] = f2bf(acc[nb][r] + bias[nb]);
    }
    __syncthreads();

    u16* dst = (which == 0) ? qo : ((which == 1) ? ko : vo);
    #pragma unroll
    for (int t = 0; t < 2; ++t) {
        int ii = tid + t * 256;
        int row = ii >> 3, c8 = (ii & 7) * 8;
        bf16x8 val = *(const bf16x8*)&Cs[row][c8];
        size_t addr = (which < 2)
            ? ((size_t)bh * S_ + s0 + row) * DK + c8
            : ((size_t)bh * DK + row) * S_ + s0 + c8;
        *(bf16x8*)&dst[addr] = val;
    }
}

// ---------------------------------------------------------------------------
// Kernel: flash attention, bf16 MFMA, NO-MAX softmax (scores bounded << 88).
// p = exp2(s * 0.125*log2e) unnormalized; row-sum in registers, one final
// shfl reduction; P stored as truncated bf16 (sum uses same truncated value).
// ---------------------------------------------------------------------------
__global__ __launch_bounds__(256) void attn_mfma(
    const u16* __restrict__ q, const u16* __restrict__ k,
    const u16* __restrict__ vt, u16* __restrict__ obf)
{
    __shared__ __align__(16) u16 Ks[4096];
    __shared__ __align__(16) u16 Vs[4096];
    __shared__ __align__(16) u16 Ps[4][1024];

    const int tid = threadIdx.x;
    const int wave = tid >> 6, lane = tid & 63;
    const int n_ = lane & 15, quad = lane >> 4;
    const int i0 = blockIdx.x * 64;
    const int hd = blockIdx.y, b = blockIdx.z;
    const int bh = b * NH + hd;

    const u16* qrow = q + ((size_t)bh * S_ + i0 + wave * 16 + n_) * DK;
    bf16x8 qf0 = *(const bf16x8*)&qrow[quad * 8];
    bf16x8 qf1 = *(const bf16x8*)&qrow[32 + quad * 8];

    const u16* kbase = k  + ((size_t)bh * S_ + wave * 16 + n_) * DK + quad * 8;
    const u16* vbase = vt + ((size_t)bh * DK + wave * 16 + n_) * S_ + quad * 8;
    u16* kslot = &Ks[wave * 1024];
    u16* vslot = &Vs[wave * 1024];
    u16* pw = Ps[wave];

    int pbase[4];
    #pragma unroll
    for (int nb = 0; nb < 4; ++nb) {
        int hp = nb >> 1;
        int qp = (nb * 2 + (n_ >> 3)) & 3;
        pbase[nb] = (hp * 64 + qp * 16) * 8 + (n_ & 7) + quad * 32;
    }

    const float SC = 0.125f * 1.44269504f;   // scale * log2(e)
    float lsum[4] = {0.f, 0.f, 0.f, 0.f};
    f32x4 oacc[4];
    #pragma unroll
    for (int nb = 0; nb < 4; ++nb)
        #pragma unroll
        for (int r = 0; r < 4; ++r) oacc[nb][r] = 0.f;

    for (int jt = 0; jt < S_; jt += 64) {
        __syncthreads();
        stage16(kbase + (size_t)jt * DK,      kslot);
        stage16(kbase + (size_t)jt * DK + 32, kslot + 512);
        stage16(vbase + jt,                   vslot);
        stage16(vbase + jt + 32,              vslot + 512);
        __syncthreads();

        f32x4 sb[4];
        #pragma unroll
        for (int nb = 0; nb < 4; ++nb) {
            f32x4 a; a[0] = a[1] = a[2] = a[3] = 0.f;
            bf16x8 kf0 = *(const bf16x8*)&Ks[nb * 1024 + lane * 8];
            bf16x8 kf1 = *(const bf16x8*)&Ks[nb * 1024 + 512 + lane * 8];
            a = __builtin_amdgcn_mfma_f32_16x16x32_bf16(qf0, kf0, a, 0, 0, 0);
            a = __builtin_amdgcn_mfma_f32_16x16x32_bf16(qf1, kf1, a, 0, 0, 0);
            sb[nb] = a;
        }

        // p = exp2(s*SC); truncate to bf16; sum the truncated value
        #pragma unroll
        for (int nb = 0; nb < 4; ++nb)
            #pragma unroll
            for (int r = 0; r < 4; ++r) {
                float p = exp2f(sb[nb][r] * SC);
                u32 bits = __float_as_uint(p) & 0xffff0000u;
                lsum[r] += __uint_as_float(bits);
                pw[pbase[nb] + r * 8] = (u16)(bits >> 16);
            }

        bf16x8 pa0 = *(const bf16x8*)&pw[lane * 8];
        bf16x8 pa1 = *(const bf16x8*)&pw[512 + lane * 8];
        #pragma unroll
        for (int nbd = 0; nbd < 4; ++nbd) {
            bf16x8 vf0 = *(const bf16x8*)&Vs[nbd * 1024 + lane * 8];
            bf16x8 vf1 = *(const bf16x8*)&Vs[nbd * 1024 + 512 + lane * 8];
            oacc[nbd] = __builtin_amdgcn_mfma_f32_16x16x32_bf16(pa0, vf0, oacc[nbd], 0, 0, 0);
            oacc[nbd] = __builtin_amdgcn_mfma_f32_16x16x32_bf16(pa1, vf1, oacc[nbd], 0, 0, 0);
        }
    }

    // final row-sum reduction across the 16-lane group
    float inv[4];
    #pragma unroll
    for (int r = 0; r < 4; ++r) {
        float s = lsum[r];
        s += __shfl_xor(s, 1);
        s += __shfl_xor(s, 2);
        s += __shfl_xor(s, 4);
        s += __shfl_xor(s, 8);
        inv[r] = 1.f / s;
    }

    #pragma unroll
    for (int nbd = 0; nbd < 4; ++nbd)
        #pragma unroll
        for (int r = 0; r < 4; ++r)
            pw[(quad * 4 + r) * 64 + nbd * 16 + n_] = f2bf(oacc[nbd][r] * inv[r]);
    #pragma unroll
    for (int t = 0; t < 2; ++t) {
        int ii = lane + t * 64;
        int row = ii >> 3, c8 = (ii & 7) * 8;
        bf16x8 vv = *(const bf16x8*)&pw[row * 64 + c8];
        *(bf16x8*)&obf[((size_t)b * S_ + i0 + wave * 16 + row) * ND + hd * DK + c8] = vv;
    }
}

// ---------------------------------------------------------------------------
// Kernel: out projection, bf16 MFMA, BK=128 + fp32 epilogue (bias+residual).
// ---------------------------------------------------------------------------
__global__ __launch_bounds__(256) void out_proj_mfma(
    const u16* __restrict__ obf, const u16* __restrict__ woT,
    const float* __restrict__ bo, const float* __restrict__ x,
    float* __restrict__ out)
{
    __shared__ __align__(16) u16 As[8192];
    __shared__ __align__(16) u16 Bs[8192];
    __shared__ __align__(16) float Ct[64][68];

    const int tid = threadIdx.x;
    const int wave = tid >> 6, lane = tid & 63;
    const int n_ = lane & 15, quad = lane >> 4;
    const int s0 = blockIdx.x * 64, c0 = blockIdx.y * 64, b = blockIdx.z;

    const u16* arow = obf + ((size_t)b * S_ + s0 + wave * 16 + n_) * ND + quad * 8;
    const u16* brow = woT + (size_t)(c0 + wave * 16 + n_) * ND + quad * 8;
    u16* aslot = &As[wave * 2048];
    u16* bslot = &Bs[wave * 2048];

    f32x4 acc[4];
    #pragma unroll
    for (int nb = 0; nb < 4; ++nb)
        #pragma unroll
        for (int r = 0; r < 4; ++r) acc[nb][r] = 0.f;

    #pragma unroll
    for (int kc = 0; kc < ND; kc += 128) {
        __syncthreads();
        #pragma unroll
        for (int c2 = 0; c2 < 4; ++c2) {
            stage16(arow + kc + c2 * 32, aslot + c2 * 512);
            stage16(brow + kc + c2 * 32, bslot + c2 * 512);
        }
        __syncthreads();
        #pragma unroll
        for (int c2 = 0; c2 < 4; ++c2) {
            bf16x8 af = *(const bf16x8*)&As[wave * 2048 + c2 * 512 + lane * 8];
            #pragma unroll
            for (int nb = 0; nb < 4; ++nb) {
                bf16x8 bf = *(const bf16x8*)&Bs[nb * 2048 + c2 * 512 + lane * 8];
                acc[nb] = __builtin_amdgcn_mfma_f32_16x16x32_bf16(af, bf, acc[nb], 0, 0, 0);
            }
        }
    }

    const int srow = wave * 16 + quad * 4;
    __syncthreads();
    #pragma unroll
    for (int nb = 0; nb < 4; ++nb)
        #pragma unroll
        for (int r = 0; r < 4; ++r)
            Ct[nb * 16 + n_][srow + r] = acc[nb][r];
    __syncthreads();

    #pragma unroll
    for (int t = 0; t < 4; ++t) {
        int ii = tid + t * 256;
        int row = ii >> 4, ch = (ii & 15) * 4;
        float4 cv = *(const float4*)&Ct[row][ch];
        float bias = bo[c0 + row];
        size_t idx = ((size_t)b * C_ + c0 + row) * S_ + s0 + ch;
        float4 xv = *(const float4*)&x[idx];
        float4 rr;
        rr.x = cv.x + bias + xv.x;
        rr.y = cv.y + bias + xv.y;
        rr.z = cv.z + bias + xv.z;
        rr.w = cv.w + bias + xv.w;
        *(float4*)&out[idx] = rr;
    }
}

// ---------------------------------------------------------------------------
extern "C" void kernel_launch(void* const* d_in, const int* in_sizes, int n_in,
                              void* d_out, int out_size, void* d_ws, size_t ws_size,
                              hipStream_t stream) {
    const float* x  = (const float*)d_in[0];
    const float* wp = (const float*)d_in[1];
    const float* bp = (const float*)d_in[2];
    const float* wo = (const float*)d_in[3];
    const float* bo = (const float*)d_in[4];
    float* out = (float*)d_out;

    const size_t QKV_E = (size_t)B_ * NH * S_ * DK;   // 4 Mi
    u16* q   = (u16*)d_ws;
    u16* kk  = q   + QKV_E;
    u16* vtp = kk  + QKV_E;
    u16* obf = vtp + QKV_E;                            // B*S*ND
    u16* xt  = obf + (size_t)B_ * S_ * ND;             // B*S*C
    u16* wpT = xt  + (size_t)B_ * S_ * C_;             // P3*C
    u16* woT = wpT + (size_t)P3 * C_;                  // C*ND

    transpose_cvt<<<dim3(S_ / 64, C_ / 64, B_), 256, 0, stream>>>(x, xt, C_, S_);
    transpose_cvt<<<dim3(P3 / 64, C_ / 64, 1), 256, 0, stream>>>(wp, wpT, C_, P3);
    transpose_cvt<<<dim3(C_ / 64, ND / 64, 1), 256, 0, stream>>>(wo, woT, ND, C_);
    qkv_mfma     <<<dim3(S_ / 64, P3 / 64, B_), 256, 0, stream>>>(xt, wpT, bp, q, kk, vtp);
    attn_mfma    <<<dim3(S_ / 64, NH, B_),      256, 0, stream>>>(q, kk, vtp, obf);
    out_proj_mfma<<<dim3(S_ / 64, C_ / 64, B_), 256, 0, stream>>>(obf, woT, bo, x, out);
}

// Round 6
// 148.292 us; speedup vs baseline: 4.9880x; 1.0539x over previous
//
#include <hip/hip_runtime.h>
#include <math.h>

#define B_  16
#define C_  256
#define S_  1024
#define NH  4
#define DK  64
#define P3  768   // 3*NH*DK
#define ND  256   // NH*DK

typedef unsigned short u16;
typedef unsigned int   u32;
typedef float  f32x4  __attribute__((ext_vector_type(4)));
typedef short  bf16x8 __attribute__((ext_vector_type(8)));

#define MFMA16(a, b, c) __builtin_amdgcn_mfma_f32_16x16x32_bf16(a, b, c, 0, 0, 0)

// fold softmax scale*log2(e) into q at projection time
#define QSCALE 0.1803368801111137f   // 0.125 * 1.44269504

__device__ __forceinline__ u16 f2bf(float f) {
    union { float f; u32 u; } x; x.f = f;
    u32 r = x.u + 0x7fffu + ((x.u >> 16) & 1u);   // RNE
    return (u16)(r >> 16);
}

// async global->LDS, 16B per lane; LDS dest is wave-uniform base + lane*16
__device__ __forceinline__ void stage16(const u16* g, u16* l) {
    __builtin_amdgcn_global_load_lds(
        (const __attribute__((address_space(1))) void*)g,
        (__attribute__((address_space(3))) void*)l, 16, 0, 0);
}

// ---------------------------------------------------------------------------
// Tiled transpose + fp32->bf16: src[z][R][Cc] -> dst[z][Cc][R]  (for x)
// ---------------------------------------------------------------------------
__global__ __launch_bounds__(256) void transpose_cvt(
    const float* __restrict__ src, u16* __restrict__ dst, int R, int Cc)
{
    __shared__ float T[64][65];
    const int tid = threadIdx.x;
    const int c0 = blockIdx.x * 64, r0 = blockIdx.y * 64, z = blockIdx.z;
    src += (size_t)z * R * Cc;
    dst += (size_t)z * R * Cc;

    const int l64 = tid & 63, rr0 = tid >> 6;
    #pragma unroll
    for (int t = 0; t < 16; ++t) {
        int rr = rr0 + t * 4;
        T[rr][l64] = src[(size_t)(r0 + rr) * Cc + c0 + l64];
    }
    __syncthreads();
    const int rp = tid & 31;
    const int cb = tid >> 5;
    #pragma unroll
    for (int t = 0; t < 8; ++t) {
        int c = cb + t * 8;
        u32 lo = f2bf(T[2 * rp][c]);
        u32 hi = f2bf(T[2 * rp + 1][c]);
        *(u32*)&dst[(size_t)(c0 + c) * R + r0 + 2 * rp] = lo | (hi << 16);
    }
}

// Both weight transposes in one launch: z=0 -> wp (256x768), z=1 -> wo (256x256)
__global__ __launch_bounds__(256) void transpose_w(
    const float* __restrict__ wp, u16* __restrict__ wpT,
    const float* __restrict__ wo, u16* __restrict__ woT)
{
    const int z = blockIdx.z;
    const int Cc = z ? 256 : 768;
    if ((int)blockIdx.x * 64 >= Cc) return;
    const float* src = z ? wo : wp;
    u16* dst = z ? woT : wpT;
    const int R = 256;

    __shared__ float T[64][65];
    const int tid = threadIdx.x;
    const int c0 = blockIdx.x * 64, r0 = blockIdx.y * 64;

    const int l64 = tid & 63, rr0 = tid >> 6;
    #pragma unroll
    for (int t = 0; t < 16; ++t) {
        int rr = rr0 + t * 4;
        T[rr][l64] = src[(size_t)(r0 + rr) * Cc + c0 + l64];
    }
    __syncthreads();
    const int rp = tid & 31;
    const int cb = tid >> 5;
    #pragma unroll
    for (int t = 0; t < 8; ++t) {
        int c = cb + t * 8;
        u32 lo = f2bf(T[2 * rp][c]);
        u32 hi = f2bf(T[2 * rp + 1][c]);
        *(u32*)&dst[(size_t)(c0 + c) * R + r0 + 2 * rp] = lo | (hi << 16);
    }
}

// ---------------------------------------------------------------------------
// QKV projection: 128(M=s) x 64(N=n) tile, 4 waves x (32x64), BK=128.
// q gets QSCALE folded in. v stored TRANSPOSED [bh][dk][s] (plain order).
// ---------------------------------------------------------------------------
__global__ __launch_bounds__(256) void qkv_mfma(
    const u16* __restrict__ xt, const u16* __restrict__ wpT,
    const float* __restrict__ bp, u16* __restrict__ qo,
    u16* __restrict__ ko, u16* __restrict__ vo)
{
    __shared__ __align__(16) u16 SM[24576];   // As 16384 (128x128) + Bs 8192 (64x128)
    u16* As = SM;
    u16* Bs = SM + 16384;

    const int tid = threadIdx.x;
    const int w = tid >> 6, lane = tid & 63;
    const int n_ = lane & 15, quad = lane >> 4;
    const int n0 = blockIdx.x * 64, s0 = blockIdx.y * 128, b = blockIdx.z;

    const u16* ar0 = xt + ((size_t)b * S_ + s0 + (2 * w + 0) * 16 + n_) * C_ + quad * 8;
    const u16* ar1 = xt + ((size_t)b * S_ + s0 + (2 * w + 1) * 16 + n_) * C_ + quad * 8;
    const u16* br  = wpT + (size_t)(n0 + w * 16 + n_) * C_ + quad * 8;

    f32x4 acc[2][4];
    #pragma unroll
    for (int am = 0; am < 2; ++am)
        #pragma unroll
        for (int nf = 0; nf < 4; ++nf)
            #pragma unroll
            for (int r = 0; r < 4; ++r) acc[am][nf][r] = 0.f;

    #pragma unroll
    for (int kb = 0; kb < 2; ++kb) {
        const int kcb = kb * 128;
        __syncthreads();
        #pragma unroll
        for (int kc = 0; kc < 4; ++kc) {
            stage16(ar0 + kcb + kc * 32, As + ((2 * w + 0) * 4 + kc) * 512);
            stage16(ar1 + kcb + kc * 32, As + ((2 * w + 1) * 4 + kc) * 512);
            stage16(br  + kcb + kc * 32, Bs + (w * 4 + kc) * 512);
        }
        __syncthreads();
        #pragma unroll
        for (int kc = 0; kc < 4; ++kc) {
            bf16x8 af0 = *(const bf16x8*)&As[((2 * w + 0) * 4 + kc) * 512 + lane * 8];
            bf16x8 af1 = *(const bf16x8*)&As[((2 * w + 1) * 4 + kc) * 512 + lane * 8];
            #pragma unroll
            for (int nf = 0; nf < 4; ++nf) {
                bf16x8 bf = *(const bf16x8*)&Bs[(nf * 4 + kc) * 512 + lane * 8];
                acc[0][nf] = MFMA16(af0, bf, acc[0][nf]);
                acc[1][nf] = MFMA16(af1, bf, acc[1][nf]);
            }
        }
    }

    const int hd = n0 / 192, rem = n0 % 192, which = rem / 64;
    const int bh = b * NH + hd;
    float bias[4];
    #pragma unroll
    for (int nf = 0; nf < 4; ++nf) bias[nf] = bp[n0 + nf * 16 + n_];
    const float sc = (which == 0) ? QSCALE : 1.f;

    __syncthreads();   // done with As/Bs, reuse SM for epilogue
    if (which < 2) {
        u16* Cs = SM;                      // [128][72]
        #pragma unroll
        for (int am = 0; am < 2; ++am) {
            int row0 = w * 32 + am * 16 + quad * 4;
            #pragma unroll
            for (int nf = 0; nf < 4; ++nf)
                #pragma unroll
                for (int r = 0; r < 4; ++r)
                    Cs[(row0 + r) * 72 + nf * 16 + n_] =
                        f2bf((acc[am][nf][r] + bias[nf]) * sc);
        }
        __syncthreads();
        u16* dst = (which == 0) ? qo : ko;
        #pragma unroll
        for (int t = 0; t < 4; ++t) {
            int ii = tid + t * 256;
            int row = ii >> 3, c8 = (ii & 7) * 8;
            *(bf16x8*)&dst[((size_t)bh * S_ + s0 + row) * DK + c8] =
                *(const bf16x8*)&Cs[row * 72 + c8];
        }
    } else {
        u16* Cs = SM;                      // [64][136] (dk-major, plain s cols)
        #pragma unroll
        for (int am = 0; am < 2; ++am) {
            int colb = w * 32 + am * 16 + quad * 4;
            #pragma unroll
            for (int nf = 0; nf < 4; ++nf)
                #pragma unroll
                for (int r = 0; r < 4; ++r)
                    Cs[(nf * 16 + n_) * 136 + colb + r] =
                        f2bf(acc[am][nf][r] + bias[nf]);
        }
        __syncthreads();
        #pragma unroll
        for (int t = 0; t < 4; ++t) {
            int ii = tid + t * 256;
            int row = ii >> 4, c8 = (ii & 15) * 8;
            *(bf16x8*)&vo[((size_t)bh * DK + row) * S_ + s0 + c8] =
                *(const bf16x8*)&Cs[row * 136 + c8];
        }
    }
}

// ---------------------------------------------------------------------------
// Flash attention: block = 128 q (4 waves x 32 q), 64-key tiles, no-max
// softmax. S computed TRANSPOSED (A=K with kappa-permuted rows, B=Q) so the
// P^T C-layout -> PV B-operand transform is a pure register repack:
//   kappa(mu,nb) = 32(nb&1) + 8(mu>>2) + 4(nb>>1) + (mu&3)
//   pa[h] = {tr[h][0..3], tr[h+2][0..3]}   (h = nb&1, keys slots identity)
// PV: O^T = V^T (A) * P^T (B); V needs NO permutation.
// ---------------------------------------------------------------------------
__global__ __launch_bounds__(256) void attn_mfma(
    const u16* __restrict__ q, const u16* __restrict__ k,
    const u16* __restrict__ vt, u16* __restrict__ obf)
{
    __shared__ __align__(16) u16 SM[9216];    // Ks 4096 + Vs 4096; epi 4x2304
    u16* Ks = SM;
    u16* Vs = SM + 4096;

    const int tid = threadIdx.x;
    const int w = tid >> 6, lane = tid & 63;
    const int n_ = lane & 15, quad = lane >> 4;
    const int i0 = blockIdx.x * 128;
    const int hd = blockIdx.y, b = blockIdx.z;
    const int bh = b * NH + hd;

    // Q fragments (B-operand; scale pre-folded): query = i0 + w*32 + am*16 + n_
    bf16x8 qf[2][2];
    #pragma unroll
    for (int am = 0; am < 2; ++am) {
        const u16* qrow = q + ((size_t)bh * S_ + i0 + w * 32 + am * 16 + n_) * DK;
        qf[am][0] = *(const bf16x8*)&qrow[quad * 8];
        qf[am][1] = *(const bf16x8*)&qrow[32 + quad * 8];
    }

    // K staging with kappa row permutation (staging wave w = MFMA block nb)
    const int kappa = 32 * (w & 1) + 8 * (n_ >> 2) + 4 * (w >> 1) + (n_ & 3);
    const u16* kbase = k  + ((size_t)bh * S_ + kappa) * DK + quad * 8;
    const u16* vbase = vt + ((size_t)bh * DK + w * 16 + n_) * S_ + quad * 8;

    float lsum[2] = {0.f, 0.f};
    f32x4 oacc[2][4];
    #pragma unroll
    for (int am = 0; am < 2; ++am)
        #pragma unroll
        for (int nd = 0; nd < 4; ++nd)
            #pragma unroll
            for (int r = 0; r < 4; ++r) oacc[am][nd][r] = 0.f;

    for (int jt = 0; jt < S_; jt += 64) {
        __syncthreads();
        stage16(kbase + (size_t)jt * DK,      Ks + w * 1024);
        stage16(kbase + (size_t)jt * DK + 32, Ks + w * 1024 + 512);
        stage16(vbase + jt,                   Vs + w * 1024);
        stage16(vbase + jt + 32,              Vs + w * 1024 + 512);
        __syncthreads();

        // S^T = K Q^T : C rows = permuted keys, cols = queries (n_)
        f32x4 sb[2][4];
        #pragma unroll
        for (int nb = 0; nb < 4; ++nb) {
            bf16x8 kf0 = *(const bf16x8*)&Ks[nb * 1024 + lane * 8];
            bf16x8 kf1 = *(const bf16x8*)&Ks[nb * 1024 + 512 + lane * 8];
            #pragma unroll
            for (int am = 0; am < 2; ++am) {
                f32x4 a; a[0] = a[1] = a[2] = a[3] = 0.f;
                a = MFMA16(kf0, qf[am][0], a);
                a = MFMA16(kf1, qf[am][1], a);
                sb[am][nb] = a;
            }
        }

        // exp2, truncate to bf16, per-lane scalar sum (query=n_ uniform),
        // register repack into PV B-operand layout
        bf16x8 pa[2][2];
        #pragma unroll
        for (int am = 0; am < 2; ++am) {
            u32 tr[4][4];
            #pragma unroll
            for (int nb = 0; nb < 4; ++nb)
                #pragma unroll
                for (int r = 0; r < 4; ++r) {
                    float p = exp2f(sb[am][nb][r]);
                    u32 bits = __float_as_uint(p) & 0xffff0000u;
                    lsum[am] += __uint_as_float(bits);
                    tr[nb][r] = bits;
                }
            union { bf16x8 v; u32 u[4]; } p0, p1;
            p0.u[0] = (tr[0][0] >> 16) | tr[0][1];
            p0.u[1] = (tr[0][2] >> 16) | tr[0][3];
            p0.u[2] = (tr[2][0] >> 16) | tr[2][1];
            p0.u[3] = (tr[2][2] >> 16) | tr[2][3];
            p1.u[0] = (tr[1][0] >> 16) | tr[1][1];
            p1.u[1] = (tr[1][2] >> 16) | tr[1][3];
            p1.u[2] = (tr[3][0] >> 16) | tr[3][1];
            p1.u[3] = (tr[3][2] >> 16) | tr[3][3];
            pa[am][0] = p0.v;
            pa[am][1] = p1.v;
        }

        // O^T += V^T P^T : A = V^T frags (key-slots identity), B = pa
        #pragma unroll
        for (int nd = 0; nd < 4; ++nd) {
            bf16x8 vf0 = *(const bf16x8*)&Vs[nd * 1024 + lane * 8];
            bf16x8 vf1 = *(const bf16x8*)&Vs[nd * 1024 + 512 + lane * 8];
            #pragma unroll
            for (int am = 0; am < 2; ++am) {
                oacc[am][nd] = MFMA16(vf0, pa[am][0], oacc[am][nd]);
                oacc[am][nd] = MFMA16(vf1, pa[am][1], oacc[am][nd]);
            }
        }
    }

    // total = sum over 4 quads (all 16 in-lane values are for query n_)
    float inv[2];
    #pragma unroll
    for (int am = 0; am < 2; ++am) {
        float s = lsum[am];
        s += __shfl_xor(s, 16);
        s += __shfl_xor(s, 32);
        inv[am] = 1.f / s;
    }

    // epilogue: O^T[dk=nd*16+quad*4+r][query=n_] -> eb[query-local][dk]
    __syncthreads();
    u16* eb = SM + w * 2304;   // [32][72]
    #pragma unroll
    for (int am = 0; am < 2; ++am)
        #pragma unroll
        for (int nd = 0; nd < 4; ++nd) {
            uint2 uv;
            uv.x = (u32)f2bf(oacc[am][nd][0] * inv[am]) |
                   ((u32)f2bf(oacc[am][nd][1] * inv[am]) << 16);
            uv.y = (u32)f2bf(oacc[am][nd][2] * inv[am]) |
                   ((u32)f2bf(oacc[am][nd][3] * inv[am]) << 16);
            *(uint2*)&eb[(am * 16 + n_) * 72 + nd * 16 + quad * 4] = uv;
        }
    __syncthreads();
    #pragma unroll
    for (int t = 0; t < 4; ++t) {
        int ii = lane + t * 64;
        int row = ii >> 3, c8 = (ii & 7) * 8;
        *(bf16x8*)&obf[((size_t)b * S_ + i0 + w * 32 + row) * ND + hd * DK + c8] =
            *(const bf16x8*)&eb[row * 72 + c8];
    }
}

// ---------------------------------------------------------------------------
// Out projection: A = woT (M=c=64), B = obf (N=s=128), BK=128.
// C[c][s] layout -> direct coalesced stores out[b][c][s] (+bias+residual).
// ---------------------------------------------------------------------------
__global__ __launch_bounds__(256) void out_proj_mfma(
    const u16* __restrict__ obf, const u16* __restrict__ woT,
    const float* __restrict__ bo, const float* __restrict__ x,
    float* __restrict__ out)
{
    __shared__ __align__(16) u16 SM[24576];   // Bs 16384 (128x128) + As 8192 (64x128)
    u16* Bs = SM;
    u16* As = SM + 16384;

    const int tid = threadIdx.x;
    const int w = tid >> 6, lane = tid & 63;
    const int n_ = lane & 15, quad = lane >> 4;
    const int c0 = blockIdx.x * 64, s0 = blockIdx.y * 128, b = blockIdx.z;

    const u16* ar  = woT + (size_t)(c0 + w * 16 + n_) * ND + quad * 8;
    const u16* br0 = obf + ((size_t)b * S_ + s0 + (2 * w + 0) * 16 + n_) * ND + quad * 8;
    const u16* br1 = obf + ((size_t)b * S_ + s0 + (2 * w + 1) * 16 + n_) * ND + quad * 8;

    f32x4 acc[2][4];
    #pragma unroll
    for (int nf = 0; nf < 2; ++nf)
        #pragma unroll
        for (int mb = 0; mb < 4; ++mb)
            #pragma unroll
            for (int r = 0; r < 4; ++r) acc[nf][mb][r] = 0.f;

    #pragma unroll
    for (int kb = 0; kb < 2; ++kb) {
        const int kcb = kb * 128;
        __syncthreads();
        #pragma unroll
        for (int kc = 0; kc < 4; ++kc) {
            stage16(ar  + kcb + kc * 32, As + (w * 4 + kc) * 512);
            stage16(br0 + kcb + kc * 32, Bs + ((2 * w + 0) * 4 + kc) * 512);
            stage16(br1 + kcb + kc * 32, Bs + ((2 * w + 1) * 4 + kc) * 512);
        }
        __syncthreads();
        #pragma unroll
        for (int kc = 0; kc < 4; ++kc) {
            bf16x8 bf0 = *(const bf16x8*)&Bs[((2 * w + 0) * 4 + kc) * 512 + lane * 8];
            bf16x8 bf1 = *(const bf16x8*)&Bs[((2 * w + 1) * 4 + kc) * 512 + lane * 8];
            #pragma unroll
            for (int mb = 0; mb < 4; ++mb) {
                bf16x8 af = *(const bf16x8*)&As[(mb * 4 + kc) * 512 + lane * 8];
                acc[0][mb] = MFMA16(af, bf0, acc[0][mb]);
                acc[1][mb] = MFMA16(af, bf1, acc[1][mb]);
            }
        }
    }

    // direct epilogue: c = c0+mb*16+quad*4+r, s = s0+w*32+nf*16+n_
    #pragma unroll
    for (int mb = 0; mb < 4; ++mb)
        #pragma unroll
        for (int r = 0; r < 4; ++r) {
            int c = c0 + mb * 16 + quad * 4 + r;
            float bias = bo[c];
            #pragma unroll
            for (int nf = 0; nf < 2; ++nf) {
                size_t idx = ((size_t)b * C_ + c) * S_ + s0 + w * 32 + nf * 16 + n_;
                out[idx] = acc[nf][mb][r] + bias + x[idx];
            }
        }
}

// ---------------------------------------------------------------------------
extern "C" void kernel_launch(void* const* d_in, const int* in_sizes, int n_in,
                              void* d_out, int out_size, void* d_ws, size_t ws_size,
                              hipStream_t stream) {
    const float* x  = (const float*)d_in[0];
    const float* wp = (const float*)d_in[1];
    const float* bp = (const float*)d_in[2];
    const float* wo = (const float*)d_in[3];
    const float* bo = (const float*)d_in[4];
    float* out = (float*)d_out;

    const size_t QKV_E = (size_t)B_ * NH * S_ * DK;   // 4 Mi
    u16* q   = (u16*)d_ws;
    u16* kk  = q   + QKV_E;
    u16* vtp = kk  + QKV_E;
    u16* obf = vtp + QKV_E;                            // B*S*ND
    u16* xt  = obf + (size_t)B_ * S_ * ND;             // B*S*C
    u16* wpT = xt  + (size_t)B_ * S_ * C_;             // P3*C
    u16* woT = wpT + (size_t)P3 * C_;                  // C*ND

    transpose_cvt<<<dim3(S_ / 64, C_ / 64, B_), 256, 0, stream>>>(x, xt, C_, S_);
    transpose_w  <<<dim3(12, 4, 2),             256, 0, stream>>>(wp, wpT, wo, woT);
    qkv_mfma     <<<dim3(P3 / 64, S_ / 128, B_), 256, 0, stream>>>(xt, wpT, bp, q, kk, vtp);
    attn_mfma    <<<dim3(S_ / 128, NH, B_),      256, 0, stream>>>(q, kk, vtp, obf);
    out_proj_mfma<<<dim3(C_ / 64, S_ / 128, B_), 256, 0, stream>>>(obf, woT, bo, x, out);
}